// Round 4
// baseline (85.331 us; speedup 1.0000x reference)
//
#include <hip/hip_runtime.h>
#include <math.h>

#define HW 4096      // 64*64
#define CS 32        // channels per branch
#define NS 128       // B*GROUPS samples
#define EPS 1e-5f

typedef float vfloat4 __attribute__((ext_vector_type(4)));

__device__ __forceinline__ float sigmoidf_(float x) {
    return 1.0f / (1.0f + __expf(-x));
}

__device__ __forceinline__ void nt_store4(float4* p, float4 v) {
    __builtin_nontemporal_store(*(const vfloat4*)&v, (vfloat4*)p);
}

// One block per (sample, branch): 1024 threads, 32 planes, 32 threads/plane.
// plane p = tid>>5 maps to one half-wave -> all reductions are 5-shfl.
__global__ __launch_bounds__(1024, 1) void fused_kernel(
    const float* __restrict__ x, float* __restrict__ out,
    const float* __restrict__ cw,  const float* __restrict__ cb,
    const float* __restrict__ sw,  const float* __restrict__ sb,
    const float* __restrict__ gnw, const float* __restrict__ gnb,
    const float* __restrict__ fc1w, const float* __restrict__ fc1b,
    const float* __restrict__ lnw, const float* __restrict__ lnb,
    const float* __restrict__ fc2w, const float* __restrict__ fc2b) {
    const int blk = blockIdx.x;
    const int n = blk >> 1, branch = blk & 1;
    const int tid = threadIdx.x;
    const int p  = tid >> 5;   // plane (channel within branch) 0..31
    const int sl = tid & 31;   // sub-lane within plane's 32-thread group

    __shared__ float muS[CS], rsS[CS], pvS[CS], g0S[CS], scS[CS];

    const size_t base4 = ((size_t)(n * 64 + branch * CS)) * 1024; // float4 units
    const float4* xp = (const float4*)x + base4 + (size_t)p * 1024;
    float4*       op = (float4*)out    + base4 + (size_t)p * 1024;

    // ---- phase 1: plane stats (the one cold HBM read) ----
    if (!branch) {
        float s = 0.f;
#pragma unroll 8
        for (int k = 0; k < 32; ++k) {
            float4 v = xp[k * 32 + sl];
            s += v.x + v.y + v.z + v.w;
        }
        for (int off = 16; off; off >>= 1) s += __shfl_down(s, off, 64);
        if (sl == 0) {
            float mean = s * (1.0f / HW);
            float g0 = sigmoidf_(cw[p] * mean + cb[p]);
            g0S[p] = g0;
            pvS[p] = mean * (1.0f - g0);       // mean of x_reid_0
        }
    } else {
        float s = 0.f, s2 = 0.f;
#pragma unroll 8
        for (int k = 0; k < 32; ++k) {
            float4 v = xp[k * 32 + sl];
            s  += v.x + v.y + v.z + v.w;
            s2 += v.x * v.x + v.y * v.y + v.z * v.z + v.w * v.w;
        }
        for (int off = 16; off; off >>= 1) {
            s  += __shfl_down(s,  off, 64);
            s2 += __shfl_down(s2, off, 64);
        }
        if (sl == 0) {
            float mu  = s * (1.0f / HW);
            float var = s2 * (1.0f / HW) - mu * mu;
            muS[p] = mu;
            rsS[p] = rsqrtf(var + EPS);
        }
    }
    __syncthreads();

    // ---- phase 2 (branch1 only): sum(xs) over each plane (cache re-read) ----
    if (branch) {
        const float mu = muS[p], rs = rsS[p];
        const float a   = gnw[p] * rs;
        const float b0  = gnb[p] - mu * a;
        const float sbv = sb[p];
        const float4* wp = (const float4*)sw + (size_t)p * 1024;
        float sx = 0.f;
#pragma unroll 4
        for (int k = 0; k < 32; ++k) {
            float4 v = xp[k * 32 + sl];
            float4 w = wp[k * 32 + sl];
            sx += v.x * sigmoidf_(w.x * (v.x * a + b0) + sbv);
            sx += v.y * sigmoidf_(w.y * (v.y * a + b0) + sbv);
            sx += v.z * sigmoidf_(w.z * (v.z * a + b0) + sbv);
            sx += v.w * sigmoidf_(w.w * (v.w * a + b0) + sbv);
        }
        for (int off = 16; off; off >>= 1) sx += __shfl_down(sx, off, 64);
        if (sl == 0) pvS[p] = mu - sx * (1.0f / HW);   // mean of x_reid_1
    }
    __syncthreads();

    // ---- phase 3: gate MLP (wave 0, lanes 0..31; shuffle-based LN) ----
    if (tid < CS) {
        const int c = tid;
        float qv = fc1b[c];
        for (int j = 0; j < CS; ++j) qv += fc1w[c * CS + j] * pvS[j];
        float bs = qv, bs2 = qv * qv;
        for (int m = 1; m < 32; m <<= 1) {
            bs  += __shfl_xor(bs,  m, 64);
            bs2 += __shfl_xor(bs2, m, 64);
        }
        float mu  = bs * (1.0f / CS);
        float var = bs2 * (1.0f / CS) - mu * mu;
        float qn  = (qv - mu) * rsqrtf(var + EPS) * lnw[c] + lnb[c];
        float r   = fmaxf(qn, 0.f);
        float sv  = fc2b[c];
        for (int j = 0; j < CS; ++j) sv += fc2w[c * CS + j] * __shfl(r, j, 64);
        float gd = sigmoidf_(sv);
        scS[c] = branch ? gd : (g0S[c] + (1.0f - g0S[c]) * gd);
    }
    __syncthreads();

    // ---- phase 4: output (cache re-read of x, nt write) ----
    const float sc = scS[p];
    if (!branch) {
#pragma unroll 8
        for (int k = 0; k < 32; ++k) {
            float4 v = xp[k * 32 + sl];
            v.x *= sc; v.y *= sc; v.z *= sc; v.w *= sc;
            nt_store4(op + k * 32 + sl, v);
        }
    } else {
        const float mu = muS[p], rs = rsS[p];
        const float a   = gnw[p] * rs;
        const float b0  = gnb[p] - mu * a;
        const float sbv = sb[p];
        const float4* wp = (const float4*)sw + (size_t)p * 1024;
#pragma unroll 4
        for (int k = 0; k < 32; ++k) {
            float4 v = xp[k * 32 + sl];
            float4 w = wp[k * 32 + sl];
            float4 o; float sg;
            sg = sigmoidf_(w.x * (v.x * a + b0) + sbv); o.x = v.x * (sg + (1.f - sg) * sc);
            sg = sigmoidf_(w.y * (v.y * a + b0) + sbv); o.y = v.y * (sg + (1.f - sg) * sc);
            sg = sigmoidf_(w.z * (v.z * a + b0) + sbv); o.z = v.z * (sg + (1.f - sg) * sc);
            sg = sigmoidf_(w.w * (v.w * a + b0) + sbv); o.w = v.w * (sg + (1.f - sg) * sc);
            nt_store4(op + k * 32 + sl, o);
        }
    }
}

extern "C" void kernel_launch(void* const* d_in, const int* in_sizes, int n_in,
                              void* d_out, int out_size, void* d_ws, size_t ws_size,
                              hipStream_t stream) {
    const float* x    = (const float*)d_in[0];
    const float* cw   = (const float*)d_in[1];
    const float* cb   = (const float*)d_in[2];
    const float* sw   = (const float*)d_in[3];
    const float* sb   = (const float*)d_in[4];
    const float* gnw  = (const float*)d_in[5];
    const float* gnb  = (const float*)d_in[6];
    const float* fc1w = (const float*)d_in[7];
    const float* fc1b = (const float*)d_in[8];
    const float* lnw  = (const float*)d_in[9];
    const float* lnb  = (const float*)d_in[10];
    const float* fc2w = (const float*)d_in[11];
    const float* fc2b = (const float*)d_in[12];
    float* out = (float*)d_out;

    fused_kernel<<<NS * 2, 1024, 0, stream>>>(x, out, cw, cb, sw, sb,
                                              gnw, gnb, fc1w, fc1b,
                                              lnw, lnb, fc2w, fc2b);
}

// Round 5
// 67.999 us; speedup vs baseline: 1.2549x; 1.2549x over previous
//
#include <hip/hip_runtime.h>
#include <math.h>

#define HW 4096      // 64*64
#define CS 32        // channels per branch
#define NS 128       // B*GROUPS samples
#define NPLANES 8192 // NS * 64
#define EPS 1e-5f

__device__ __forceinline__ float sigmoidf_(float x) {
    return 1.0f / (1.0f + __expf(-x));
}

// block-wide (256 thr, 4 waves) sum reduce; result valid in all threads
__device__ __forceinline__ float block_reduce(float s, float* ls, int tid) {
    for (int off = 32; off > 0; off >>= 1) s += __shfl_down(s, off, 64);
    const int wave = tid >> 6, lane = tid & 63;
    if (lane == 0) ls[wave] = s;
    __syncthreads();
    return ls[0] + ls[1] + ls[2] + ls[3];
}

// ---------------- K1: one read of x.
// branch0 plane -> channel sum; branch1 plane -> mu, rs, sum(xs) (reg-staged)
__global__ __launch_bounds__(256) void pass1_kernel(
    const float* __restrict__ x,
    const float* __restrict__ gnw, const float* __restrict__ gnb,
    const float* __restrict__ sw,  const float* __restrict__ sb,
    float* __restrict__ sums0, float* __restrict__ mu1,
    float* __restrict__ rs1,   float* __restrict__ sumxs) {
    const int P = blockIdx.x;
    const int n = P >> 6, cc = P & 63;
    const int tid = threadIdx.x;
    const float4* xp = (const float4*)(x + (size_t)P * HW);
    __shared__ float ls[4];
    __shared__ float bc[2];

    if (cc < CS) {
        float s = 0.f;
#pragma unroll
        for (int k = 0; k < 4; ++k) {
            float4 v = xp[tid + k * 256];
            s += v.x + v.y + v.z + v.w;
        }
        s = block_reduce(s, ls, tid);
        if (tid == 0) sums0[n * CS + cc] = s;
    } else {
        const int c = cc - CS;
        float4 v[4];
        float s = 0.f, s2 = 0.f;
#pragma unroll
        for (int k = 0; k < 4; ++k) {
            v[k] = xp[tid + k * 256];
            s  += v[k].x + v[k].y + v[k].z + v[k].w;
            s2 += v[k].x * v[k].x + v[k].y * v[k].y
                + v[k].z * v[k].z + v[k].w * v[k].w;
        }
        for (int off = 32; off > 0; off >>= 1) {
            s  += __shfl_down(s, off, 64);
            s2 += __shfl_down(s2, off, 64);
        }
        __shared__ float ls2[4];
        const int wave = tid >> 6, lane = tid & 63;
        if (lane == 0) { ls[wave] = s; ls2[wave] = s2; }
        __syncthreads();
        if (tid == 0) {
            float st  = ls[0] + ls[1] + ls[2] + ls[3];
            float s2t = ls2[0] + ls2[1] + ls2[2] + ls2[3];
            float mu  = st * (1.0f / HW);
            float var = s2t * (1.0f / HW) - mu * mu;
            float rs  = rsqrtf(var + EPS);
            mu1[n * CS + c] = mu;
            rs1[n * CS + c] = rs;
            bc[0] = mu; bc[1] = rs;
        }
        __syncthreads();
        const float mu = bc[0], rs = bc[1];
        const float a  = gnw[c] * rs;
        const float b0 = gnb[c] - mu * a;
        const float sbv = sb[c];
        const float4* wp = (const float4*)(sw + (size_t)c * HW);
        float sx = 0.f;
#pragma unroll
        for (int k = 0; k < 4; ++k) {
            float4 w = wp[tid + k * 256];
            sx += v[k].x * sigmoidf_(w.x * (v[k].x * a + b0) + sbv);
            sx += v[k].y * sigmoidf_(w.y * (v[k].y * a + b0) + sbv);
            sx += v[k].z * sigmoidf_(w.z * (v[k].z * a + b0) + sbv);
            sx += v[k].w * sigmoidf_(w.w * (v[k].w * a + b0) + sbv);
        }
        __syncthreads();   // ls reuse
        sx = block_reduce(sx, ls, tid);
        if (tid == 0) sumxs[n * CS + c] = sx;
    }
}

// ---------------- K2: fused gates + output pass (both branches)
__global__ __launch_bounds__(256) void out_kernel(
    const float* __restrict__ x, float* __restrict__ out,
    const float* __restrict__ sums0,
    const float* __restrict__ mu1, const float* __restrict__ rs1,
    const float* __restrict__ sumxs,
    const float* __restrict__ cw,  const float* __restrict__ cb,
    const float* __restrict__ gnw, const float* __restrict__ gnb,
    const float* __restrict__ sw,  const float* __restrict__ sb,
    const float* __restrict__ fc1w, const float* __restrict__ fc1b,
    const float* __restrict__ lnw, const float* __restrict__ lnb,
    const float* __restrict__ fc2w, const float* __restrict__ fc2b) {
    const int P = blockIdx.x;
    const int n = P >> 6, cc = P & 63;
    const int tid = threadIdx.x;
    const int branch = (cc >= CS);
    const int c0 = cc & 31;

    __shared__ float pS[CS], qS[CS], rS[CS], g0S[CS];
    __shared__ float scaleS;

    // ---- redundant per-block gate MLP (threads of wave 0) ----
    if (tid < CS) {
        float pv;
        if (!branch) {
            float mean = sums0[n * CS + tid] * (1.0f / HW);
            float g0 = sigmoidf_(cw[tid] * mean + cb[tid]);
            g0S[tid] = g0;
            pv = mean * (1.0f - g0);          // mean of x_reid_0
        } else {
            pv = mu1[n * CS + tid] - sumxs[n * CS + tid] * (1.0f / HW);
        }
        pS[tid] = pv;
    }
    __syncthreads();
    if (tid < CS) {
        float qv = fc1b[tid];
        for (int j = 0; j < CS; ++j) qv += fc1w[tid * CS + j] * pS[j];
        qS[tid] = qv;
    }
    __syncthreads();
    if (tid < CS) {
        float mu = 0.f;
        for (int j = 0; j < CS; ++j) mu += qS[j];
        mu *= (1.0f / CS);
        float var = 0.f;
        for (int j = 0; j < CS; ++j) { float d = qS[j] - mu; var += d * d; }
        var *= (1.0f / CS);
        float qn = (qS[tid] - mu) * rsqrtf(var + EPS) * lnw[tid] + lnb[tid];
        rS[tid] = fmaxf(qn, 0.f);
    }
    __syncthreads();
    if (tid < 64) {   // whole wave 0 active -> well-defined shuffles
        float t = (tid < CS) ? fc2w[c0 * CS + tid] * rS[tid] : 0.f;
        for (int off = 32; off > 0; off >>= 1) t += __shfl_down(t, off, 64);
        if (tid == 0) {
            float gd = sigmoidf_(t + fc2b[c0]);
            scaleS = branch ? gd : (g0S[c0] + (1.0f - g0S[c0]) * gd);
        }
    }
    __syncthreads();

    const float4* xp = (const float4*)(x + (size_t)P * HW);
    float4* op = (float4*)(out + (size_t)P * HW);

    if (!branch) {
        const float scale = scaleS;
#pragma unroll
        for (int k = 0; k < 4; ++k) {
            float4 v = xp[tid + k * 256];
            v.x *= scale; v.y *= scale; v.z *= scale; v.w *= scale;
            op[tid + k * 256] = v;   // normal store: overwrite poison in-cache
        }
    } else {
        const float g  = scaleS;
        const float mu = mu1[n * CS + c0], rs = rs1[n * CS + c0];
        const float a  = gnw[c0] * rs;
        const float b0 = gnb[c0] - mu * a;
        const float sbv = sb[c0];
        const float4* wp = (const float4*)(sw + (size_t)c0 * HW);
#pragma unroll
        for (int k = 0; k < 4; ++k) {
            float4 v = xp[tid + k * 256];
            float4 w = wp[tid + k * 256];
            float4 o; float sg;
            sg = sigmoidf_(w.x * (v.x * a + b0) + sbv); o.x = v.x * (sg + (1.f - sg) * g);
            sg = sigmoidf_(w.y * (v.y * a + b0) + sbv); o.y = v.y * (sg + (1.f - sg) * g);
            sg = sigmoidf_(w.z * (v.z * a + b0) + sbv); o.z = v.z * (sg + (1.f - sg) * g);
            sg = sigmoidf_(w.w * (v.w * a + b0) + sbv); o.w = v.w * (sg + (1.f - sg) * g);
            op[tid + k * 256] = o;   // normal store
        }
    }
}

extern "C" void kernel_launch(void* const* d_in, const int* in_sizes, int n_in,
                              void* d_out, int out_size, void* d_ws, size_t ws_size,
                              hipStream_t stream) {
    const float* x    = (const float*)d_in[0];
    const float* cw   = (const float*)d_in[1];
    const float* cb   = (const float*)d_in[2];
    const float* sw   = (const float*)d_in[3];
    const float* sb   = (const float*)d_in[4];
    const float* gnw  = (const float*)d_in[5];
    const float* gnb  = (const float*)d_in[6];
    const float* fc1w = (const float*)d_in[7];
    const float* fc1b = (const float*)d_in[8];
    const float* lnw  = (const float*)d_in[9];
    const float* lnb  = (const float*)d_in[10];
    const float* fc2w = (const float*)d_in[11];
    const float* fc2b = (const float*)d_in[12];
    float* out = (float*)d_out;
    float* ws  = (float*)d_ws;

    float* sums0 = ws;             // 4096
    float* mu1   = ws + 4096;      // 4096
    float* rs1   = ws + 8192;      // 4096
    float* sumxs = ws + 12288;     // 4096

    pass1_kernel<<<NPLANES, 256, 0, stream>>>(x, gnw, gnb, sw, sb,
                                              sums0, mu1, rs1, sumxs);
    out_kernel<<<NPLANES, 256, 0, stream>>>(x, out, sums0, mu1, rs1, sumxs,
                                            cw, cb, gnw, gnb, sw, sb,
                                            fc1w, fc1b, lnw, lnb, fc2w, fc2b);
}